// Round 1
// baseline (7340.626 us; speedup 1.0000x reference)
//
#include <hip/hip_runtime.h>

#define DEVI __device__ __forceinline__

typedef __attribute__((ext_vector_type(8))) short bf8;
typedef __attribute__((ext_vector_type(4))) float f4;

DEVI unsigned short f2bf(float f) {
  union { float f; unsigned u; } v; v.f = f;
  unsigned r = v.u + 0x7fffu + ((v.u >> 16) & 1u);
  return (unsigned short)(r >> 16);
}
DEVI float bf2f(unsigned short b) {
  union { unsigned u; float f; } v; v.u = ((unsigned)b) << 16;
  return v.f;
}
DEVI float sigmoidf_(float x) { return 1.f / (1.f + __expf(-x)); }
DEVI float tanhf_(float x) {
  float ax = fabsf(x);
  float e = __expf(-2.f * ax);
  float t = (1.f - e) / (1.f + e);
  return x < 0.f ? -t : t;
}

#define GLDS16(g, l) __builtin_amdgcn_global_load_lds( \
    (const __attribute__((address_space(1))) void*)(g), \
    (__attribute__((address_space(3))) void*)(l), 16, 0, 0)

// ---------------- conversion kernels ----------------

__global__ void k_conv_emb(const float* __restrict__ emb, unsigned short* __restrict__ ep) {
  int i = blockIdx.x * 256 + threadIdx.x;            // 10000 * 128
  if (i >= 10000 * 128) return;
  int r = i >> 7, c = i & 127;
  ep[i] = (c < 100) ? f2bf(emb[r * 100 + c]) : (unsigned short)0;
}

// column permutation: original col n = gate*1024 + u  ->
// n' = (u/32)*128 + ((u%32)/16)*64 + gate*16 + (u%16)
DEVI int permn(int n) {
  int g = n >> 10, u = n & 1023;
  return (u >> 5) * 128 + ((u >> 4) & 1) * 64 + g * 16 + (u & 15);
}

__global__ void k_conv_w0(const float* __restrict__ W0, const float* __restrict__ U0,
                          unsigned short* __restrict__ WT) {
  int i = blockIdx.x * 256 + threadIdx.x;            // 4096 * 1152
  if (i >= 4096 * 1152) return;
  int n = i / 1152, k = i - n * 1152;
  float v;
  if (k < 100) v = W0[k * 4096 + n];
  else if (k < 128) v = 0.f;
  else v = U0[(k - 128) * 4096 + n];
  WT[(size_t)permn(n) * 1152 + k] = f2bf(v);
}

__global__ void k_conv_w1(const float* __restrict__ W1, const float* __restrict__ U1,
                          unsigned short* __restrict__ WT) {
  int i = blockIdx.x * 256 + threadIdx.x;            // 4096 * 2048
  if (i >= 4096 * 2048) return;
  int n = i >> 11, k = i & 2047;
  float v = (k < 1024) ? W1[k * 4096 + n] : U1[(k - 1024) * 4096 + n];
  WT[(size_t)permn(n) * 2048 + k] = f2bf(v);
}

// ---------------- fused LSTM step: Z = [src1|src2] @ Wc^T, gates, c/h update --

template<int K1, int KTOT, bool GATHER>
__global__ __launch_bounds__(256, 2) void k_lstm(
    const unsigned short* __restrict__ src1,   // embp (gathered) or h0
    const unsigned short* __restrict__ src2,   // h0_prev or h1_prev
    const int* __restrict__ idx, int t,
    const unsigned short* __restrict__ WT,     // [4096][KTOT] bf16, permuted rows
    const float* __restrict__ bias,            // [4096] original layout
    float* __restrict__ cbuf,                  // [2048][1024] fp32, in-place
    unsigned short* __restrict__ hout)         // [2048][1024] bf16
{
  __shared__ unsigned short lA[128 * 64];
  __shared__ unsigned short lB[128 * 64];
  __shared__ int sidx[128];

  const int tid = threadIdx.x;
  const int bn = blockIdx.x & 31;
  const int bm = blockIdx.x >> 5;
  const int m0 = bm * 128;
  const int n0 = bn * 128;

  if (GATHER && tid < 128) sidx[tid] = idx[(m0 + tid) * 80 + t];
  __syncthreads();

  const int lr = tid >> 3;            // staging row-in-pass 0..31
  const int k8 = (tid & 7) * 8;       // element offset of this lane's 16B chunk

  const unsigned short* a1b[4];
  const unsigned short* a2b[4];
  const unsigned short* bb[4];
#pragma unroll
  for (int p = 0; p < 4; ++p) {
    int ra = p * 32 + lr;
    int grow = GATHER ? sidx[ra] : (m0 + ra);
    a1b[p] = src1 + (size_t)grow * K1 + k8;
    a2b[p] = src2 + (size_t)(m0 + ra) * 1024 + k8;
    bb[p]  = WT   + (size_t)(n0 + ra) * KTOT + k8;
  }

  const int lane = tid & 63;
  const int wv = tid >> 6;
  const int wm = wv >> 1;     // wave m-half (0..1)
  const int wn = wv & 1;      // wave n-half (0..1)
  const int cl = lane & 15;
  const int qd = lane >> 4;

  f4 acc[4][4];
  const f4 fz = {0.f, 0.f, 0.f, 0.f};
#pragma unroll
  for (int a = 0; a < 4; ++a)
#pragma unroll
    for (int b = 0; b < 4; ++b) acc[a][b] = fz;

  constexpr int NKB = KTOT / 64;
#pragma unroll 1
  for (int kb = 0; kb < NKB; ++kb) {
    const int kc = kb * 64 + k8;
#pragma unroll
    for (int p = 0; p < 4; ++p) {
      const unsigned short* g =
          (kc < K1) ? (a1b[p] + kb * 64) : (a2b[p] + (kb * 64 - K1));
      GLDS16(g, &lA[p * 2048 + tid * 8]);
    }
#pragma unroll
    for (int p = 0; p < 4; ++p) {
      GLDS16(bb[p] + kb * 64, &lB[p * 2048 + tid * 8]);
    }
    __syncthreads();
#pragma unroll
    for (int kk = 0; kk < 2; ++kk) {
      bf8 af[4], bfr[4];
#pragma unroll
      for (int mi = 0; mi < 4; ++mi)
        af[mi] = *(const bf8*)&lA[(wm * 64 + mi * 16 + cl) * 64 + kk * 32 + qd * 8];
#pragma unroll
      for (int j = 0; j < 4; ++j)
        bfr[j] = *(const bf8*)&lB[(wn * 64 + j * 16 + cl) * 64 + kk * 32 + qd * 8];
#pragma unroll
      for (int mi = 0; mi < 4; ++mi)
#pragma unroll
        for (int j = 0; j < 4; ++j)
          acc[mi][j] = __builtin_amdgcn_mfma_f32_16x16x32_bf16(
              af[mi], bfr[j], acc[mi][j], 0, 0, 0);
    }
    __syncthreads();
  }

  // epilogue: per-lane holds z_i, z_f, z_g, z_o (j = gate) for unit u
  const int u = bn * 32 + wn * 16 + cl;
  const float bi = bias[u];
  const float bff = bias[1024 + u];
  const float bg = bias[2048 + u];
  const float bo = bias[3072 + u];
#pragma unroll
  for (int mi = 0; mi < 4; ++mi) {
    int mbase = m0 + wm * 64 + mi * 16 + qd * 4;
#pragma unroll
    for (int r = 0; r < 4; ++r) {
      int m = mbase + r;
      float gi = sigmoidf_(acc[mi][0][r] + bi);
      float gf = sigmoidf_(acc[mi][1][r] + bff);
      float gg = tanhf_(acc[mi][2][r] + bg);
      float go = sigmoidf_(acc[mi][3][r] + bo);
      size_t off = (size_t)m * 1024 + u;
      float cn = gf * cbuf[off] + gi * gg;
      cbuf[off] = cn;
      hout[off] = f2bf(go * tanhf_(cn));
    }
  }
}

// ---------------- final FC + sigmoid ----------------

__global__ void k_fc(const unsigned short* __restrict__ h1,
                     const float* __restrict__ fcW, const float* __restrict__ fcb,
                     float* __restrict__ out) {
  int wv = threadIdx.x >> 6;
  int lane = threadIdx.x & 63;
  int row = blockIdx.x * 4 + wv;
  if (row >= 2048) return;
  const unsigned short* hr = h1 + (size_t)row * 1024;
  float s = 0.f;
  for (int k = lane; k < 1024; k += 64) s += bf2f(hr[k]) * fcW[k];
#pragma unroll
  for (int off = 32; off > 0; off >>= 1) s += __shfl_down(s, off);
  if (lane == 0) out[row] = sigmoidf_(s + fcb[0]);
}

// ---------------- launcher ----------------

extern "C" void kernel_launch(void* const* d_in, const int* in_sizes, int n_in,
                              void* d_out, int out_size, void* d_ws, size_t ws_size,
                              hipStream_t stream) {
  const int*   idx = (const int*)d_in[0];
  const float* emb = (const float*)d_in[1];
  const float* W0  = (const float*)d_in[2];
  const float* U0  = (const float*)d_in[3];
  const float* b0  = (const float*)d_in[4];
  const float* W1  = (const float*)d_in[5];
  const float* U1  = (const float*)d_in[6];
  const float* b1  = (const float*)d_in[7];
  const float* fcW = (const float*)d_in[8];
  const float* fcb = (const float*)d_in[9];
  float* out = (float*)d_out;

  char* ws = (char*)d_ws;
  unsigned short* embp = (unsigned short*)(ws);                    //  2,560,000
  unsigned short* WT0  = (unsigned short*)(ws + 2560000);          //  9,437,184
  unsigned short* WT1  = (unsigned short*)(ws + 11997184);         // 16,777,216
  unsigned short* h0b[2] = {(unsigned short*)(ws + 28774400),
                            (unsigned short*)(ws + 32968704)};     // 2x 4,194,304
  unsigned short* h1b[2] = {(unsigned short*)(ws + 37163008),
                            (unsigned short*)(ws + 41357312)};     // 2x 4,194,304
  float* c0 = (float*)(ws + 45551616);                             //  8,388,608
  float* c1 = (float*)(ws + 53940224);                             //  8,388,608
  // total: 62,328,832 bytes

  // zero h (both buffers) and c
  hipMemsetAsync(ws + 28774400, 0, 33554432, stream);

  k_conv_emb<<<5000, 256, 0, stream>>>(emb, embp);
  k_conv_w0<<<18432, 256, 0, stream>>>(W0, U0, WT0);
  k_conv_w1<<<32768, 256, 0, stream>>>(W1, U1, WT1);

  for (int t = 0; t < 80; ++t) {
    unsigned short* h0i = h0b[(t + 1) & 1];
    unsigned short* h0o = h0b[t & 1];
    unsigned short* h1i = h1b[(t + 1) & 1];
    unsigned short* h1o = h1b[t & 1];
    k_lstm<128, 1152, true><<<512, 256, 0, stream>>>(
        embp, h0i, idx, t, WT0, b0, c0, h0o);
    k_lstm<1024, 2048, false><<<512, 256, 0, stream>>>(
        h0o, h1i, nullptr, 0, WT1, b1, c1, h1o);
  }

  k_fc<<<512, 256, 0, stream>>>(h1b[1], fcW, fcb, out);
}

// Round 2
// 5619.868 us; speedup vs baseline: 1.3062x; 1.3062x over previous
//
#include <hip/hip_runtime.h>

#define DEVI __device__ __forceinline__

typedef __attribute__((ext_vector_type(8))) short bf8;
typedef __attribute__((ext_vector_type(4))) float f4;

DEVI unsigned short f2bf(float f) {
  union { float f; unsigned u; } v; v.f = f;
  unsigned r = v.u + 0x7fffu + ((v.u >> 16) & 1u);
  return (unsigned short)(r >> 16);
}
DEVI float bf2f(unsigned short b) {
  union { unsigned u; float f; } v; v.u = ((unsigned)b) << 16;
  return v.f;
}
DEVI float sigmoidf_(float x) { return 1.f / (1.f + __expf(-x)); }
DEVI float tanhf_(float x) {
  float ax = fabsf(x);
  float e = __expf(-2.f * ax);
  float t = (1.f - e) / (1.f + e);
  return x < 0.f ? -t : t;
}

#define GLDS16(g, l) __builtin_amdgcn_global_load_lds( \
    (const __attribute__((address_space(1))) void*)(g), \
    (__attribute__((address_space(3))) void*)(l), 16, 0, 0)

// ---------------- conversion kernels ----------------

__global__ void k_conv_emb(const float* __restrict__ emb, unsigned short* __restrict__ ep) {
  int i = blockIdx.x * 256 + threadIdx.x;            // 10000 * 128
  if (i >= 10000 * 128) return;
  int r = i >> 7, c = i & 127;
  ep[i] = (c < 100) ? f2bf(emb[r * 100 + c]) : (unsigned short)0;
}

// column permutation: original col n = gate*1024 + u  ->
// n' = (u/32)*128 + ((u%32)/16)*64 + gate*16 + (u%16)
DEVI int permn(int n) {
  int g = n >> 10, u = n & 1023;
  return (u >> 5) * 128 + ((u >> 4) & 1) * 64 + g * 16 + (u & 15);
}

__global__ void k_conv_w0(const float* __restrict__ W0, const float* __restrict__ U0,
                          unsigned short* __restrict__ WT) {
  int i = blockIdx.x * 256 + threadIdx.x;            // 4096 * 1152
  if (i >= 4096 * 1152) return;
  int n = i / 1152, k = i - n * 1152;
  float v;
  if (k < 100) v = W0[k * 4096 + n];
  else if (k < 128) v = 0.f;
  else v = U0[(k - 128) * 4096 + n];
  WT[(size_t)permn(n) * 1152 + k] = f2bf(v);
}

__global__ void k_conv_w1(const float* __restrict__ W1, const float* __restrict__ U1,
                          unsigned short* __restrict__ WT) {
  int i = blockIdx.x * 256 + threadIdx.x;            // 4096 * 2048
  if (i >= 4096 * 2048) return;
  int n = i >> 11, k = i & 2047;
  float v = (k < 1024) ? W1[k * 4096 + n] : U1[(k - 1024) * 4096 + n];
  WT[(size_t)permn(n) * 2048 + k] = f2bf(v);
}

// ---------------- fused LSTM step: Z = [src1|src2] @ Wc^T, gates, c/h update --
//
// LDS bank-conflict swizzle: LDS[r][c] (16B chunks, c=0..7) holds global chunk
// c ^ (r&7). Staging applies the XOR on the GLOBAL address (LDS side is pinned
// to wave-uniform base + lane*16 by global_load_lds); readers XOR the chunk
// index with (cl&7). Permutation stays inside each 128B row -> same cachelines,
// and never crosses the src1/src2 K boundary (K1 % 64 == 0).

template<int K1, int KTOT, bool GATHER>
__global__ __launch_bounds__(256, 2) void k_lstm(
    const unsigned short* __restrict__ src1,   // embp (gathered) or h0
    const unsigned short* __restrict__ src2,   // h0_prev or h1_prev
    const int* __restrict__ idx, int t,
    const unsigned short* __restrict__ WT,     // [4096][KTOT] bf16, permuted rows
    const float* __restrict__ bias,            // [4096] original layout
    float* __restrict__ cbuf,                  // [2048][1024] fp32, in-place
    unsigned short* __restrict__ hout)         // [2048][1024] bf16
{
  __shared__ unsigned short lA[128 * 64];
  __shared__ unsigned short lB[128 * 64];
  __shared__ int sidx[128];

  const int tid = threadIdx.x;
  const int bn = blockIdx.x & 31;
  const int bm = blockIdx.x >> 5;
  const int m0 = bm * 128;
  const int n0 = bn * 128;

  if (GATHER && tid < 128) sidx[tid] = idx[(m0 + tid) * 80 + t];
  __syncthreads();

  const int lr = tid >> 3;                  // staging row-in-pass 0..31
  // swizzled global chunk offset: chunk' = (tid&7) ^ (row&7); row&7 == lr&7
  const int k8 = (((tid & 7) ^ (lr & 7)) * 8);

  const unsigned short* a1b[4];
  const unsigned short* a2b[4];
  const unsigned short* bb[4];
#pragma unroll
  for (int p = 0; p < 4; ++p) {
    int ra = p * 32 + lr;
    int grow = GATHER ? sidx[ra] : (m0 + ra);
    a1b[p] = src1 + (size_t)grow * K1 + k8;
    a2b[p] = src2 + (size_t)(m0 + ra) * 1024 + k8;
    bb[p]  = WT   + (size_t)(n0 + ra) * KTOT + k8;
  }

  const int lane = tid & 63;
  const int wv = tid >> 6;
  const int wm = wv >> 1;     // wave m-half (0..1)
  const int wn = wv & 1;      // wave n-half (0..1)
  const int cl = lane & 15;
  const int qd = lane >> 4;
  const int swr = (cl & 7) << 3;  // read-side XOR, pre-scaled to elements

  f4 acc[4][4];
  const f4 fz = {0.f, 0.f, 0.f, 0.f};
#pragma unroll
  for (int a = 0; a < 4; ++a)
#pragma unroll
    for (int b = 0; b < 4; ++b) acc[a][b] = fz;

  constexpr int NKB = KTOT / 64;
#pragma unroll 1
  for (int kb = 0; kb < NKB; ++kb) {
#pragma unroll
    for (int p = 0; p < 4; ++p) {
      const unsigned short* g =
          (kb * 64 < K1) ? (a1b[p] + kb * 64) : (a2b[p] + (kb * 64 - K1));
      GLDS16(g, &lA[p * 2048 + tid * 8]);
    }
#pragma unroll
    for (int p = 0; p < 4; ++p) {
      GLDS16(bb[p] + kb * 64, &lB[p * 2048 + tid * 8]);
    }
    __syncthreads();
#pragma unroll
    for (int kk = 0; kk < 2; ++kk) {
      bf8 af[4], bfr[4];
#pragma unroll
      for (int mi = 0; mi < 4; ++mi)
        af[mi] = *(const bf8*)&lA[(wm * 64 + mi * 16 + cl) * 64 +
                                  (((kk * 32 + qd * 8) ^ swr))];
#pragma unroll
      for (int j = 0; j < 4; ++j)
        bfr[j] = *(const bf8*)&lB[(wn * 64 + j * 16 + cl) * 64 +
                                  (((kk * 32 + qd * 8) ^ swr))];
#pragma unroll
      for (int mi = 0; mi < 4; ++mi)
#pragma unroll
        for (int j = 0; j < 4; ++j)
          acc[mi][j] = __builtin_amdgcn_mfma_f32_16x16x32_bf16(
              af[mi], bfr[j], acc[mi][j], 0, 0, 0);
    }
    __syncthreads();
  }

  // epilogue: per-lane holds z_i, z_f, z_g, z_o (j = gate) for unit u
  const int u = bn * 32 + wn * 16 + cl;
  const float bi = bias[u];
  const float bff = bias[1024 + u];
  const float bg = bias[2048 + u];
  const float bo = bias[3072 + u];
#pragma unroll
  for (int mi = 0; mi < 4; ++mi) {
    int mbase = m0 + wm * 64 + mi * 16 + qd * 4;
#pragma unroll
    for (int r = 0; r < 4; ++r) {
      int m = mbase + r;
      float gi = sigmoidf_(acc[mi][0][r] + bi);
      float gf = sigmoidf_(acc[mi][1][r] + bff);
      float gg = tanhf_(acc[mi][2][r] + bg);
      float go = sigmoidf_(acc[mi][3][r] + bo);
      size_t off = (size_t)m * 1024 + u;
      float cn = gf * cbuf[off] + gi * gg;
      cbuf[off] = cn;
      hout[off] = f2bf(go * tanhf_(cn));
    }
  }
}

// ---------------- final FC + sigmoid ----------------

__global__ void k_fc(const unsigned short* __restrict__ h1,
                     const float* __restrict__ fcW, const float* __restrict__ fcb,
                     float* __restrict__ out) {
  int wv = threadIdx.x >> 6;
  int lane = threadIdx.x & 63;
  int row = blockIdx.x * 4 + wv;
  if (row >= 2048) return;
  const unsigned short* hr = h1 + (size_t)row * 1024;
  float s = 0.f;
  for (int k = lane; k < 1024; k += 64) s += bf2f(hr[k]) * fcW[k];
#pragma unroll
  for (int off = 32; off > 0; off >>= 1) s += __shfl_down(s, off);
  if (lane == 0) out[row] = sigmoidf_(s + fcb[0]);
}

// ---------------- launcher ----------------

extern "C" void kernel_launch(void* const* d_in, const int* in_sizes, int n_in,
                              void* d_out, int out_size, void* d_ws, size_t ws_size,
                              hipStream_t stream) {
  const int*   idx = (const int*)d_in[0];
  const float* emb = (const float*)d_in[1];
  const float* W0  = (const float*)d_in[2];
  const float* U0  = (const float*)d_in[3];
  const float* b0  = (const float*)d_in[4];
  const float* W1  = (const float*)d_in[5];
  const float* U1  = (const float*)d_in[6];
  const float* b1  = (const float*)d_in[7];
  const float* fcW = (const float*)d_in[8];
  const float* fcb = (const float*)d_in[9];
  float* out = (float*)d_out;

  char* ws = (char*)d_ws;
  unsigned short* embp = (unsigned short*)(ws);                    //  2,560,000
  unsigned short* WT0  = (unsigned short*)(ws + 2560000);          //  9,437,184
  unsigned short* WT1  = (unsigned short*)(ws + 11997184);         // 16,777,216
  unsigned short* h0b[2] = {(unsigned short*)(ws + 28774400),
                            (unsigned short*)(ws + 32968704)};     // 2x 4,194,304
  unsigned short* h1b[2] = {(unsigned short*)(ws + 37163008),
                            (unsigned short*)(ws + 41357312)};     // 2x 4,194,304
  float* c0 = (float*)(ws + 45551616);                             //  8,388,608
  float* c1 = (float*)(ws + 53940224);                             //  8,388,608
  // total: 62,328,832 bytes

  // zero h (both buffers) and c
  hipMemsetAsync(ws + 28774400, 0, 33554432, stream);

  k_conv_emb<<<5000, 256, 0, stream>>>(emb, embp);
  k_conv_w0<<<18432, 256, 0, stream>>>(W0, U0, WT0);
  k_conv_w1<<<32768, 256, 0, stream>>>(W1, U1, WT1);

  for (int t = 0; t < 80; ++t) {
    unsigned short* h0i = h0b[(t + 1) & 1];
    unsigned short* h0o = h0b[t & 1];
    unsigned short* h1i = h1b[(t + 1) & 1];
    unsigned short* h1o = h1b[t & 1];
    k_lstm<128, 1152, true><<<512, 256, 0, stream>>>(
        embp, h0i, idx, t, WT0, b0, c0, h0o);
    k_lstm<1024, 2048, false><<<512, 256, 0, stream>>>(
        h0o, h1i, nullptr, 0, WT1, b1, c1, h1o);
  }

  k_fc<<<512, 256, 0, stream>>>(h1b[1], fcW, fcb, out);
}

// Round 3
// 5105.733 us; speedup vs baseline: 1.4377x; 1.1007x over previous
//
#include <hip/hip_runtime.h>

#define DEVI __device__ __forceinline__

typedef __attribute__((ext_vector_type(8))) short bf8;
typedef __attribute__((ext_vector_type(4))) float f4;

DEVI unsigned short f2bf(float f) {
  union { float f; unsigned u; } v; v.f = f;
  unsigned r = v.u + 0x7fffu + ((v.u >> 16) & 1u);
  return (unsigned short)(r >> 16);
}
DEVI float bf2f(unsigned short b) {
  union { unsigned u; float f; } v; v.u = ((unsigned)b) << 16;
  return v.f;
}
DEVI float sigmoidf_(float x) { return 1.f / (1.f + __expf(-x)); }
DEVI float tanhf_(float x) {
  float ax = fabsf(x);
  float e = __expf(-2.f * ax);
  float t = (1.f - e) / (1.f + e);
  return x < 0.f ? -t : t;
}

#define GLDS16(g, l) __builtin_amdgcn_global_load_lds( \
    (const __attribute__((address_space(1))) void*)(g), \
    (__attribute__((address_space(3))) void*)(l), 16, 0, 0)

// ---------------- conversion kernels ----------------

__global__ void k_conv_emb(const float* __restrict__ emb, unsigned short* __restrict__ ep) {
  int i = blockIdx.x * 256 + threadIdx.x;            // 10000 * 128
  if (i >= 10000 * 128) return;
  int r = i >> 7, c = i & 127;
  ep[i] = (c < 100) ? f2bf(emb[r * 100 + c]) : (unsigned short)0;
}

// column permutation: original col n = gate*1024 + u  ->
// n' = (u/32)*128 + ((u%32)/16)*64 + gate*16 + (u%16)
DEVI int permn(int n) {
  int g = n >> 10, u = n & 1023;
  return (u >> 5) * 128 + ((u >> 4) & 1) * 64 + g * 16 + (u & 15);
}

__global__ void k_conv_w0(const float* __restrict__ W0, const float* __restrict__ U0,
                          unsigned short* __restrict__ WT) {
  int i = blockIdx.x * 256 + threadIdx.x;            // 4096 * 1152
  if (i >= 4096 * 1152) return;
  int n = i / 1152, k = i - n * 1152;
  float v;
  if (k < 100) v = W0[k * 4096 + n];
  else if (k < 128) v = 0.f;
  else v = U0[(k - 128) * 4096 + n];
  WT[(size_t)permn(n) * 1152 + k] = f2bf(v);
}

__global__ void k_conv_w1(const float* __restrict__ W1, const float* __restrict__ U1,
                          unsigned short* __restrict__ WT) {
  int i = blockIdx.x * 256 + threadIdx.x;            // 4096 * 2048
  if (i >= 4096 * 2048) return;
  int n = i >> 11, k = i & 2047;
  float v = (k < 1024) ? W1[k * 4096 + n] : U1[(k - 1024) * 4096 + n];
  WT[(size_t)permn(n) * 2048 + k] = f2bf(v);
}

// ---------------- fused LSTM step body --------------------------------------
// Double-buffered K-loop, prefetch-after-barrier:
//   stage(0); for kb: { __syncthreads(); stage(kb+1); compute(kb); }
// The __syncthreads drain (vmcnt(0)) waits ONLY on the loads issued last
// iteration, which had a full compute phase to land. stage(kb+1) writes the
// buffer last read at iter kb-1 — safe because the barrier at kb guarantees
// all waves finished iter kb-1's compute.
// LDS swizzle as in r2: chunk' = chunk ^ (row&7) applied on the global side.

template<int K1, int KTOT, bool GATHER>
__device__ void lstm_body(int blk, char* smem,
    const unsigned short* __restrict__ src1,   // embp (gathered) or h0(t-1)
    const unsigned short* __restrict__ src2,   // h prev (recurrent input)
    const int* __restrict__ idx, int t,
    const unsigned short* __restrict__ WT,     // [4096][KTOT] bf16, permuted rows
    const float* __restrict__ bias,            // [4096] original layout
    float* __restrict__ cbuf,                  // [2048][1024] fp32, in-place
    unsigned short* __restrict__ hout)         // [2048][1024] bf16
{
  const int tid = threadIdx.x;
  const int bn = blk & 31;
  const int bm = blk >> 5;
  const int m0 = bm * 128;
  const int n0 = bn * 128;

  const int lr = tid >> 3;                       // staging row-in-pass 0..31
  const int k8 = ((tid & 7) ^ (lr & 7)) * 8;     // swizzled chunk offset

  const unsigned short* a1b[4];
  const unsigned short* a2b[4];
  const unsigned short* bb[4];
#pragma unroll
  for (int p = 0; p < 4; ++p) {
    int ra = p * 32 + lr;
    int grow = GATHER ? idx[(m0 + ra) * 80 + t] : (m0 + ra);
    a1b[p] = src1 + (size_t)grow * K1 + k8;
    a2b[p] = src2 + (size_t)(m0 + ra) * 1024 + k8;
    bb[p]  = WT   + (size_t)(n0 + ra) * KTOT + k8;
  }

  unsigned short* const LA0 = (unsigned short*)smem;
  unsigned short* const LB0 = (unsigned short*)(smem + 16384);
  unsigned short* const LA1 = (unsigned short*)(smem + 32768);
  unsigned short* const LB1 = (unsigned short*)(smem + 49152);

  auto stage = [&](int kb) {
    unsigned short* la = (kb & 1) ? LA1 : LA0;
    unsigned short* lb = (kb & 1) ? LB1 : LB0;
#pragma unroll
    for (int p = 0; p < 4; ++p) {
      const unsigned short* g = (kb * 64 < K1) ? (a1b[p] + kb * 64)
                                               : (a2b[p] + (kb * 64 - K1));
      GLDS16(g, &la[p * 2048 + tid * 8]);
    }
#pragma unroll
    for (int p = 0; p < 4; ++p)
      GLDS16(bb[p] + kb * 64, &lb[p * 2048 + tid * 8]);
  };

  const int lane = tid & 63;
  const int wv = tid >> 6;
  const int wm = wv >> 1;     // wave m-half (0..1)
  const int wn = wv & 1;      // wave n-half (0..1)
  const int cl = lane & 15;
  const int qd = lane >> 4;
  const int swr = (cl & 7) << 3;  // read-side XOR, pre-scaled to elements

  f4 acc[4][4];
  const f4 fz = {0.f, 0.f, 0.f, 0.f};
#pragma unroll
  for (int a = 0; a < 4; ++a)
#pragma unroll
    for (int b = 0; b < 4; ++b) acc[a][b] = fz;

  stage(0);

  constexpr int NKB = KTOT / 64;
#pragma unroll 1
  for (int kb = 0; kb < NKB; ++kb) {
    __syncthreads();                      // drains only last iter's 8 loads
    if (kb + 1 < NKB) stage(kb + 1);      // prefetch next K-block
    unsigned short* la = (kb & 1) ? LA1 : LA0;
    unsigned short* lb = (kb & 1) ? LB1 : LB0;
#pragma unroll
    for (int kk = 0; kk < 2; ++kk) {
      bf8 af[4], bfr[4];
#pragma unroll
      for (int mi = 0; mi < 4; ++mi)
        af[mi] = *(const bf8*)&la[(wm * 64 + mi * 16 + cl) * 64 +
                                  ((kk * 32 + qd * 8) ^ swr)];
#pragma unroll
      for (int j = 0; j < 4; ++j)
        bfr[j] = *(const bf8*)&lb[(wn * 64 + j * 16 + cl) * 64 +
                                  ((kk * 32 + qd * 8) ^ swr)];
#pragma unroll
      for (int mi = 0; mi < 4; ++mi)
#pragma unroll
        for (int j = 0; j < 4; ++j)
          acc[mi][j] = __builtin_amdgcn_mfma_f32_16x16x32_bf16(
              af[mi], bfr[j], acc[mi][j], 0, 0, 0);
    }
  }

  // epilogue: per-lane holds z_i, z_f, z_g, z_o (j = gate) for unit u
  const int u = bn * 32 + wn * 16 + cl;
  const float bi = bias[u];
  const float bff = bias[1024 + u];
  const float bg = bias[2048 + u];
  const float bo = bias[3072 + u];
#pragma unroll
  for (int mi = 0; mi < 4; ++mi) {
    int mbase = m0 + wm * 64 + mi * 16 + qd * 4;
#pragma unroll
    for (int r = 0; r < 4; ++r) {
      int m = mbase + r;
      float gi = sigmoidf_(acc[mi][0][r] + bi);
      float gf = sigmoidf_(acc[mi][1][r] + bff);
      float gg = tanhf_(acc[mi][2][r] + bg);
      float go = sigmoidf_(acc[mi][3][r] + bo);
      size_t off = (size_t)m * 1024 + u;
      float cn = gf * cbuf[off] + gi * gg;
      cbuf[off] = cn;
      hout[off] = f2bf(go * tanhf_(cn));
    }
  }
}

// Fused step: blocks [0, nL1) run layer-1 at time t-1; blocks [nL1, grid) run
// layer-0 at time t. Both depend only on state produced by the previous
// dispatch, so they are independent.
__global__ __launch_bounds__(256, 2) void k_step(
    int nL1,
    const unsigned short* embp, const unsigned short* h0in,
    const int* idx, int t,
    const unsigned short* WT0, const float* b0, float* c0, unsigned short* h0out,
    const unsigned short* h0prev, const unsigned short* h1in,
    const unsigned short* WT1, const float* b1, float* c1, unsigned short* h1out)
{
  extern __shared__ char smem[];
  int blk = blockIdx.x;
  if (blk < nL1)
    lstm_body<1024, 2048, false>(blk, smem, h0prev, h1in, nullptr, 0,
                                 WT1, b1, c1, h1out);
  else
    lstm_body<128, 1152, true>(blk - nL1, smem, embp, h0in, idx, t,
                               WT0, b0, c0, h0out);
}

// ---------------- final FC + sigmoid ----------------

__global__ void k_fc(const unsigned short* __restrict__ h1,
                     const float* __restrict__ fcW, const float* __restrict__ fcb,
                     float* __restrict__ out) {
  int wv = threadIdx.x >> 6;
  int lane = threadIdx.x & 63;
  int row = blockIdx.x * 4 + wv;
  if (row >= 2048) return;
  const unsigned short* hr = h1 + (size_t)row * 1024;
  float s = 0.f;
  for (int k = lane; k < 1024; k += 64) s += bf2f(hr[k]) * fcW[k];
#pragma unroll
  for (int off = 32; off > 0; off >>= 1) s += __shfl_down(s, off);
  if (lane == 0) out[row] = sigmoidf_(s + fcb[0]);
}

// ---------------- launcher ----------------

extern "C" void kernel_launch(void* const* d_in, const int* in_sizes, int n_in,
                              void* d_out, int out_size, void* d_ws, size_t ws_size,
                              hipStream_t stream) {
  const int*   idx = (const int*)d_in[0];
  const float* emb = (const float*)d_in[1];
  const float* W0  = (const float*)d_in[2];
  const float* U0  = (const float*)d_in[3];
  const float* b0  = (const float*)d_in[4];
  const float* W1  = (const float*)d_in[5];
  const float* U1  = (const float*)d_in[6];
  const float* b1  = (const float*)d_in[7];
  const float* fcW = (const float*)d_in[8];
  const float* fcb = (const float*)d_in[9];
  float* out = (float*)d_out;

  char* ws = (char*)d_ws;
  unsigned short* embp = (unsigned short*)(ws);                    //  2,560,000
  unsigned short* WT0  = (unsigned short*)(ws + 2560000);          //  9,437,184
  unsigned short* WT1  = (unsigned short*)(ws + 11997184);         // 16,777,216
  unsigned short* h0b[2] = {(unsigned short*)(ws + 28774400),
                            (unsigned short*)(ws + 32968704)};     // 2x 4,194,304
  unsigned short* h1b[2] = {(unsigned short*)(ws + 37163008),
                            (unsigned short*)(ws + 41357312)};     // 2x 4,194,304
  float* c0 = (float*)(ws + 45551616);                             //  8,388,608
  float* c1 = (float*)(ws + 53940224);                             //  8,388,608
  // total: 62,328,832 bytes

  // zero h (both buffers of both layers) and c
  hipMemsetAsync(ws + 28774400, 0, 33554432, stream);

  k_conv_emb<<<5000, 256, 0, stream>>>(emb, embp);
  k_conv_w0<<<18432, 256, 0, stream>>>(W0, U0, WT0);
  k_conv_w1<<<32768, 256, 0, stream>>>(W1, U1, WT1);

  // t = 0: layer-0 only
  k_step<<<512, 256, 65536, stream>>>(0, embp, h0b[1], idx, 0,
                                      WT0, b0, c0, h0b[0],
                                      nullptr, nullptr, WT1, b1, c1, nullptr);
  // t = 1..79: fused [layer-1(t-1) | layer-0(t)]
  for (int t = 1; t < 80; ++t) {
    k_step<<<1024, 256, 65536, stream>>>(512, embp, h0b[(t + 1) & 1], idx, t,
                                         WT0, b0, c0, h0b[t & 1],
                                         h0b[(t - 1) & 1], h1b[t & 1],
                                         WT1, b1, c1, h1b[(t + 1) & 1]);
  }
  // final: layer-1 at t=79 (src1 = h0b[1], in h1b[0], out h1b[1])
  k_step<<<512, 256, 65536, stream>>>(512, nullptr, nullptr, nullptr, 0,
                                      WT0, b0, c0, nullptr,
                                      h0b[1], h1b[0], WT1, b1, c1, h1b[1]);

  k_fc<<<512, 256, 0, stream>>>(h1b[1], fcW, fcb, out);
}